// Round 14
// baseline (587.377 us; speedup 1.0000x reference)
//
#include <hip/hip_runtime.h>
#include <cstdint>

#define BB 2048
#define TT 200
#define DD 128
#define H1 128
#define H2 64
#define MASK_PAD -4294967295.0f

typedef __attribute__((ext_vector_type(8))) short short8;
typedef __attribute__((ext_vector_type(4))) float floatx4;

// ws layout (float offsets)
#define WS_WQAC   0          // fp32 [128][128]  Wqac[d][h] = W0a+W0c
#define WS_WCATT  16384      // bf16 [128][256]  WcatT[h][k]
#define WS_W1TB   32768      // bf16 [64][128]   W1^T
#define WS_QAS    36864      // fp32 [2048][128] qA (incl b0)
#define WS_LOGITS 299008     // fp32 [200][2048] raw logits, T-MAJOR

static __device__ __forceinline__ unsigned short f2bf(float x) {
  union { float f; unsigned int u; } v; v.f = x;
  unsigned int r = v.u + 0x7FFF + ((v.u >> 16) & 1);  // RNE
  return (unsigned short)(r >> 16);
}

// ---------------------------------------------------------------------------
// Fold: Wqac (fp32), WcatT = [(W0b-W0c); W0d]^T (bf16 [128 h][256 k]),
//       W1tb = W1^T (bf16 [64 g][128 h]).
// ---------------------------------------------------------------------------
__global__ __launch_bounds__(256) void din_fold(
    const float* __restrict__ W0, const float* __restrict__ W1,
    float* __restrict__ ws) {
  int i = blockIdx.x * blockDim.x + threadIdx.x;
  if (i < 16384) {
    int d = i >> 7, h = i & 127;
    ws[WS_WQAC + i] = W0[d * 128 + h] + W0[(256 + d) * 128 + h];
  } else if (i < 49152) {
    int j = i - 16384;           // [h][k]
    int h = j >> 8, k = j & 255;
    float v;
    if (k < 128) v = W0[(128 + k) * 128 + h] - W0[(256 + k) * 128 + h];
    else         v = W0[(384 + (k - 128)) * 128 + h];
    ((unsigned short*)(ws + WS_WCATT))[j] = f2bf(v);
  } else if (i < 57344) {
    int j = i - 49152;           // [g][h]
    int g = j >> 7, h = j & 127;
    ((unsigned short*)(ws + WS_W1TB))[j] = f2bf(W1[h * 64 + g]);
  }
}

// ---------------------------------------------------------------------------
// QA: qas_g[b][h] = b0[h] + sum_d q[b][d] * Wqac[d][h]
// ---------------------------------------------------------------------------
__global__ __launch_bounds__(128) void din_qa(
    const float* __restrict__ query, const float* __restrict__ b0,
    const float* __restrict__ ws, float* __restrict__ qas_g) {
  const int b = blockIdx.x;
  const int h = threadIdx.x;
  __shared__ float qsh[DD];
  qsh[h] = query[(size_t)b * DD + h];
  __syncthreads();
  float acc = b0[h];
  const float* wq = ws + WS_WQAC + h;
  #pragma unroll 8
  for (int d = 0; d < DD; ++d) acc += qsh[d] * wq[d * 128];
  qas_g[(size_t)b * H1 + h] = acc;
}

// ---------------------------------------------------------------------------
// Logits: T-MAJOR flat GEMM. 256 blocks x 512 threads (8 waves, 1 block/CU).
// Block: b-chunk c = blockIdx&127 (16 b's), t-half = blockIdx>>7 (100 t's).
// Stage WcatT(64K)+W1T(16K) swizzled in LDS once (only barrier). Wave w owns
// t = thalf*100 + w, w+8, ... Per-tile: everything per-b (fq, qv) is in regs
// (constant over the wave's t-loop); a0/a1 are 12 scalars (t fixed); zero
// clamps. A2 wave-private -> no barriers in loop.
// ---------------------------------------------------------------------------
__global__ __launch_bounds__(512, 1) void din_logits(
    const float* __restrict__ key, const float* __restrict__ query,
    const float* __restrict__ ws, const float* __restrict__ qas_g,
    const float* __restrict__ a0, const float* __restrict__ a1,
    const float* __restrict__ b1, const float* __restrict__ Wout,
    const float* __restrict__ bout, float* __restrict__ lgout) {
  const int tid = threadIdx.x;
  const int w = tid >> 6;        // 0..7
  const int l = tid & 63;
  const int lr = l & 15;
  const int kgrp = l >> 4;

  __shared__ unsigned short WC[128 * 256];    // 64 KB swizzled WcatT
  __shared__ unsigned short W1S[64 * 128];    // 16 KB swizzled W1T
  __shared__ unsigned short A2[8][16 * 128];  // 32 KB wave-private

  // ---- stage WC and W1S (swizzled), once per block ----
  {
    const unsigned short* wcsrc = (const unsigned short*)(ws + WS_WCATT);
    #pragma unroll
    for (int i = 0; i < 8; ++i) {
      int c = i * 512 + tid;               // 16B chunk id
      int h = c >> 5, c8 = c & 31;
      int4 v = *(const int4*)(wcsrc + c * 8);
      *(int4*)((char*)WC + h * 512 + ((c8 * 16) ^ ((h & 7) << 4))) = v;
    }
    const unsigned short* w1src = (const unsigned short*)(ws + WS_W1TB);
    #pragma unroll
    for (int i = 0; i < 2; ++i) {
      int c = i * 512 + tid;
      int g = c >> 4, c16 = c & 15;
      int4 v = *(const int4*)(w1src + c * 8);
      *(int4*)((char*)W1S + g * 256 + ((c16 * 16) ^ ((g & 7) << 4))) = v;
    }
  }
  __syncthreads();   // ONLY barrier

  const int c = blockIdx.x & 127;         // b-chunk
  const int thalf = blockIdx.x >> 7;      // 0/1
  const int b16 = c * 16;
  char* a2b = (char*)A2[w];

  // ---- per-lane persistent state (constant over t-loop) ----
  // q slice for A-row b16+lr (feeds q*k)
  float4 fq[8];
  {
    const float* qr = query + (size_t)(b16 + lr) * DD + kgrp * 8;
    #pragma unroll
    for (int ks = 0; ks < 4; ++ks) {
      fq[2 * ks]     = *(const float4*)(qr + ks * 32);
      fq[2 * ks + 1] = *(const float4*)(qr + ks * 32 + 4);
    }
  }
  // qA for C rows b16+kgrp*4+r at cols nt*16+lr
  float qv[8][4];
  #pragma unroll
  for (int nt = 0; nt < 8; ++nt) {
    #pragma unroll
    for (int r = 0; r < 4; ++r)
      qv[nt][r] = qas_g[(size_t)(b16 + kgrp * 4 + r) * H1 + nt * 16 + lr];
  }
  float b1v[4], wov[4];
  #pragma unroll
  for (int nt = 0; nt < 4; ++nt) {
    int g = nt * 16 + lr;
    b1v[nt] = b1[g]; wov[nt] = Wout[g];
  }
  const float bout0 = bout[0];

  const int tend = thalf * 100 + 100;
  int t = thalf * 100 + w;

  // ---- prologue: prefetch first tile's key slice (row b16+lr, this t) ----
  float4 fa[8];
  {
    const float* kr = key + ((size_t)(b16 + lr) * TT + t) * DD + kgrp * 8;
    #pragma unroll
    for (int ks = 0; ks < 4; ++ks) {
      fa[2 * ks]     = *(const float4*)(kr + ks * 32);
      fa[2 * ks + 1] = *(const float4*)(kr + ks * 32 + 4);
    }
  }

  // =============== barrier-free per-wave t-loop ===============
  #pragma unroll 1
  while (t < tend) {
    // ---- cvt prefetched key -> af[8]: ks 0-3 = k, 4-7 = q*k ----
    short8 af[8];
    #pragma unroll
    for (int ks = 0; ks < 4; ++ks) {
      float4 k0 = fa[2 * ks], k1 = fa[2 * ks + 1];
      float4 q0 = fq[2 * ks], q1 = fq[2 * ks + 1];
      short8 ak, aq;
      ak[0] = (short)f2bf(k0.x); ak[1] = (short)f2bf(k0.y);
      ak[2] = (short)f2bf(k0.z); ak[3] = (short)f2bf(k0.w);
      ak[4] = (short)f2bf(k1.x); ak[5] = (short)f2bf(k1.y);
      ak[6] = (short)f2bf(k1.z); ak[7] = (short)f2bf(k1.w);
      aq[0] = (short)f2bf(q0.x * k0.x); aq[1] = (short)f2bf(q0.y * k0.y);
      aq[2] = (short)f2bf(q0.z * k0.z); aq[3] = (short)f2bf(q0.w * k0.w);
      aq[4] = (short)f2bf(q1.x * k1.x); aq[5] = (short)f2bf(q1.y * k1.y);
      aq[6] = (short)f2bf(q1.z * k1.z); aq[7] = (short)f2bf(q1.w * k1.w);
      af[ks] = ak; af[ks + 4] = aq;
    }
    // ---- prefetch NEXT t's key slice (dup read on last iter, harmless) ----
    {
      int tn = t + 8; if (tn >= tend) tn = t;
      const float* kr = key + ((size_t)(b16 + lr) * TT + tn) * DD + kgrp * 8;
      #pragma unroll
      for (int ks = 0; ks < 4; ++ks) {
        fa[2 * ks]     = *(const float4*)(kr + ks * 32);
        fa[2 * ks + 1] = *(const float4*)(kr + ks * 32 + 4);
      }
    }
    // ---- this tile's alphas (t fixed -> per-lane scalars) ----
    float a0v[8], a1v[4];
    #pragma unroll
    for (int nt = 0; nt < 8; ++nt) a0v[nt] = a0[t * H1 + nt * 16 + lr];
    #pragma unroll
    for (int nt = 0; nt < 4; ++nt) a1v[nt] = a1[t * H2 + nt * 16 + lr];

    // ---- GEMM1: 8 ksteps x 8 n-tiles, B from swizzled LDS, C-init = qA ----
    floatx4 acc1[8];
    #pragma unroll
    for (int nt = 0; nt < 8; ++nt) {
      acc1[nt][0] = qv[nt][0]; acc1[nt][1] = qv[nt][1];
      acc1[nt][2] = qv[nt][2]; acc1[nt][3] = qv[nt][3];
    }
    #pragma unroll
    for (int ks = 0; ks < 8; ++ks) {
      #pragma unroll
      for (int nt = 0; nt < 8; ++nt) {
        int row = nt * 16 + lr;
        short8 bf = *(const short8*)((const char*)WC + row * 512 +
                                     ((ks * 64 + kgrp * 16) ^ ((row & 7) << 4)));
        acc1[nt] = __builtin_amdgcn_mfma_f32_16x16x32_bf16(af[ks], bf, acc1[nt], 0, 0, 0);
      }
    }

    // ---- epilogue 1: PReLU(a0), write H0 to wave-private LDS (swz) ----
    #pragma unroll
    for (int nt = 0; nt < 8; ++nt) {
      int h = nt * 16 + lr;
      float a = a0v[nt];
      #pragma unroll
      for (int r = 0; r < 4; ++r) {
        int t_loc = kgrp * 4 + r;
        float v = acc1[nt][r];
        v = v > 0.0f ? v : a * v;
        *(unsigned short*)(a2b + t_loc * 256 + ((h * 2) ^ ((t_loc & 7) << 4))) = f2bf(v);
      }
    }

    // ---- GEMM2: A from private LDS, B from swizzled LDS W1S ----
    short8 a2f[4];
    #pragma unroll
    for (int ks = 0; ks < 4; ++ks) {
      a2f[ks] = *(const short8*)(a2b + lr * 256 +
                                 ((ks * 64 + kgrp * 16) ^ ((lr & 7) << 4)));
    }
    floatx4 acc2[4];
    #pragma unroll
    for (int nt = 0; nt < 4; ++nt) acc2[nt] = (floatx4)(0.0f);
    #pragma unroll
    for (int ks = 0; ks < 4; ++ks) {
      #pragma unroll
      for (int nt = 0; nt < 4; ++nt) {
        int row = nt * 16 + lr;
        short8 bf = *(const short8*)((const char*)W1S + row * 256 +
                                     ((ks * 64 + kgrp * 16) ^ ((row & 7) << 4)));
        acc2[nt] = __builtin_amdgcn_mfma_f32_16x16x32_bf16(a2f[ks], bf, acc2[nt], 0, 0, 0);
      }
    }

    // ---- epilogue 2: +b1, PReLU(a1), *Wout, 16-lane reduce -> logits ----
    float p[4] = {0.f, 0.f, 0.f, 0.f};
    #pragma unroll
    for (int nt = 0; nt < 4; ++nt) {
      float a = a1v[nt];
      #pragma unroll
      for (int r = 0; r < 4; ++r) {
        float x = acc2[nt][r] + b1v[nt];
        x = x > 0.0f ? x : a * x;
        p[r] += x * wov[nt];
      }
    }
    #pragma unroll
    for (int m = 1; m < 16; m <<= 1) {
      #pragma unroll
      for (int r = 0; r < 4; ++r) p[r] += __shfl_xor(p[r], m);
    }
    if (lr == 0) {
      #pragma unroll
      for (int r = 0; r < 4; ++r)
        lgout[(size_t)t * BB + b16 + kgrp * 4 + r] = bout0 + p[r];
    }
    t += 8;
  }
}

// ---------------------------------------------------------------------------
// PV (+mask+softmax): logits are T-MAJOR (logits[t][b]).
// ---------------------------------------------------------------------------
__global__ __launch_bounds__(256) void din_pv(
    const float* __restrict__ val, const int* __restrict__ mask,
    const float* __restrict__ logits, float* __restrict__ out) {
  const int b = blockIdx.x;
  const int tid = threadIdx.x;
  const int w = tid >> 6;
  const int l = tid & 63;
  __shared__ float eL[TT];
  __shared__ float red4[8];
  __shared__ float red[8 * DD];

  float lv = -INFINITY;
  if (tid < TT) {
    float lg = logits[(size_t)tid * BB + b];
    int mk = mask[(size_t)b * TT + tid];
    lv = (mk == 0) ? MASK_PAD : lg;
  }
  {
    float m = lv;
    #pragma unroll
    for (int off = 32; off >= 1; off >>= 1) m = fmaxf(m, __shfl_xor(m, off));
    if (l == 0) red4[w] = m;
  }
  __syncthreads();
  float mx = fmaxf(fmaxf(red4[0], red4[1]), fmaxf(red4[2], red4[3]));
  float e = (tid < TT) ? __expf(lv - mx) : 0.0f;
  {
    float s = e;
    #pragma unroll
    for (int off = 32; off >= 1; off >>= 1) s += __shfl_xor(s, off);
    if (l == 0) red4[4 + w] = s;
  }
  __syncthreads();
  float inv = 1.0f / (red4[4] + red4[5] + red4[6] + red4[7]);
  if (tid < TT) eL[tid] = e * inv;
  __syncthreads();

  const int group = tid >> 5;
  const int d4 = (tid & 31) * 4;
  const float* vb = val + (size_t)b * TT * DD;
  float4 acc4 = make_float4(0.f, 0.f, 0.f, 0.f);
  #pragma unroll 5
  for (int t = group * 25; t < group * 25 + 25; ++t) {
    float4 v = *(const float4*)(vb + (size_t)t * DD + d4);
    float wt = eL[t];
    acc4.x += wt * v.x; acc4.y += wt * v.y;
    acc4.z += wt * v.z; acc4.w += wt * v.w;
  }
  *(float4*)&red[group * DD + d4] = acc4;
  __syncthreads();
  if (tid < DD) {
    float s = 0.0f;
    #pragma unroll
    for (int g = 0; g < 8; ++g) s += red[g * DD + tid];
    out[(size_t)b * DD + tid] = s;
  }
}

extern "C" void kernel_launch(void* const* d_in, const int* in_sizes, int n_in,
                              void* d_out, int out_size, void* d_ws, size_t ws_size,
                              hipStream_t stream) {
  const float* query = (const float*)d_in[0];
  const float* key   = (const float*)d_in[1];
  const float* val   = (const float*)d_in[2];
  const int*   mask  = (const int*)d_in[3];
  const float* W0    = (const float*)d_in[4];
  const float* b0    = (const float*)d_in[5];
  const float* a0    = (const float*)d_in[6];
  const float* W1    = (const float*)d_in[7];
  const float* b1    = (const float*)d_in[8];
  const float* a1    = (const float*)d_in[9];
  const float* Wout  = (const float*)d_in[10];
  const float* bout  = (const float*)d_in[11];
  float* out = (float*)d_out;
  float* ws  = (float*)d_ws;
  float* qas_g  = ws + WS_QAS;
  float* logits = ws + WS_LOGITS;

  hipLaunchKernelGGL(din_fold, dim3(224), dim3(256), 0, stream, W0, W1, ws);
  hipLaunchKernelGGL(din_qa, dim3(BB), dim3(128), 0, stream, query, b0, ws, qas_g);
  hipLaunchKernelGGL(din_logits, dim3(256), dim3(512), 0, stream,
                     key, query, ws, qas_g, a0, a1, b1, Wout, bout, logits);
  hipLaunchKernelGGL(din_pv, dim3(BB), dim3(256), 0, stream, val, mask, logits, out);
}

// Round 15
// 274.676 us; speedup vs baseline: 2.1384x; 2.1384x over previous
//
#include <hip/hip_runtime.h>
#include <cstdint>

#define BB 2048
#define TT 200
#define DD 128
#define H1 128
#define H2 64
#define MASK_PAD -4294967295.0f

typedef __attribute__((ext_vector_type(8))) short short8;
typedef __attribute__((ext_vector_type(4))) float floatx4;

// ws layout (float offsets)
#define WS_WQAC   0          // fp32 [128][128]  Wqac[d][h] = W0a+W0c
#define WS_WKT    16384      // fp32 [128][128]  WkT[h][d]  = (W0b-W0c)^T
#define WS_WDT    32768      // fp32 [128][128]  WdT[h][d]  = W0d^T
#define WS_W1TB   49152      // bf16 [64][128]   W1^T  (4096 float slots)
#define WS_A0T    53248      // fp32 [128][200]  a0^T  (25600)
#define WS_A1T    78848      // fp32 [64][200]   a1^T  (12800)
#define WS_QAS    91648      // fp32 [2048][128] qA    (262144)
#define WS_ATTN   353792     // fp32 [2048][200] attn  (409600)

static __device__ __forceinline__ unsigned short f2bf(float x) {
  union { float f; unsigned int u; } v; v.f = x;
  unsigned int r = v.u + 0x7FFF + ((v.u >> 16) & 1);  // RNE
  return (unsigned short)(r >> 16);
}

// ---------------------------------------------------------------------------
// Fold: weight reshapes/transposes (one-time, tiny)
// ---------------------------------------------------------------------------
__global__ __launch_bounds__(256) void din_fold(
    const float* __restrict__ W0, const float* __restrict__ W1,
    const float* __restrict__ a0, const float* __restrict__ a1,
    float* __restrict__ ws) {
  int i = blockIdx.x * blockDim.x + threadIdx.x;
  if (i < 16384) {
    int d = i >> 7, h = i & 127;
    ws[WS_WQAC + i] = W0[d * 128 + h] + W0[(256 + d) * 128 + h];
    ws[WS_WKT + (h * 128 + d)] = W0[(128 + d) * 128 + h] - W0[(256 + d) * 128 + h];
    ws[WS_WDT + (h * 128 + d)] = W0[(384 + d) * 128 + h];
  } else if (i < 24576) {
    int j = i - 16384; int g = j >> 7, h = j & 127;
    ((unsigned short*)(ws + WS_W1TB))[j] = f2bf(W1[h * 64 + g]);
  } else if (i < 50176) {
    int j = i - 24576; int h = j / 200, t = j % 200;
    ws[WS_A0T + j] = a0[t * H1 + h];
  } else if (i < 62976) {
    int j = i - 50176; int g = j / 200, t = j % 200;
    ws[WS_A1T + j] = a1[t * H2 + g];
  }
}

// ---------------------------------------------------------------------------
// QA: qas_g[b][h] = b0[h] + sum_d q[b][d] * Wqac[d][h]
// ---------------------------------------------------------------------------
__global__ __launch_bounds__(128) void din_qa(
    const float* __restrict__ query, const float* __restrict__ b0,
    const float* __restrict__ ws, float* __restrict__ qas_g) {
  const int b = blockIdx.x;
  const int h = threadIdx.x;
  __shared__ float qsh[DD];
  qsh[h] = query[(size_t)b * DD + h];
  __syncthreads();
  float acc = b0[h];
  const float* wq = ws + WS_WQAC + h;
  #pragma unroll 8
  for (int d = 0; d < DD; ++d) acc += qsh[d] * wq[d * 128];
  qas_g[(size_t)b * H1 + h] = acc;
}

// ---------------------------------------------------------------------------
// Logits+softmax: 512 blocks x 4 waves; wave w owns b = blk*4+w END-TO-END.
// Whole grid resident at once (2 blocks/CU). B1f (q-folded GEMM1 weights) in
// 128 VGPRs per wave; A direct from key; wave-private LDS transpose; GEMM2 B
// from block-shared W1S LDS (one barrier); wave-local softmax via shfl.
// 2-pass accumulator keeps live set < 256 VGPR.
// ---------------------------------------------------------------------------
__global__ __launch_bounds__(256, 2) void din_logits(
    const float* __restrict__ key, const float* __restrict__ query,
    const int* __restrict__ mask, const float* __restrict__ ws,
    const float* __restrict__ qas_g,
    const float* __restrict__ b1, const float* __restrict__ Wout,
    const float* __restrict__ bout, float* __restrict__ attn_out) {
  const int tid = threadIdx.x;
  const int w = tid >> 6;
  const int l = tid & 63;
  const int lr = l & 15;
  const int kgrp = l >> 4;

  __shared__ unsigned short W1S[64 * 128];    // 16 KB swizzled W1^T
  __shared__ unsigned short A2[4][16 * 128];  // 16 KB wave-private
  __shared__ float LG[4][208];                // wave-private logits

  // ---- stage W1S (swizzled) ----
  {
    const unsigned short* w1src = (const unsigned short*)(ws + WS_W1TB);
    #pragma unroll
    for (int i = 0; i < 4; ++i) {
      int c = i * 256 + tid;               // 16B chunk id, 1024 total
      int g = c >> 4, c16 = c & 15;
      int4 v = *(const int4*)(w1src + c * 8);
      *(int4*)((char*)W1S + g * 256 + ((c16 * 16) ^ ((g & 7) << 4))) = v;
    }
  }
  __syncthreads();   // only barrier

  const int b = blockIdx.x * 4 + w;
  char* a2b = (char*)A2[w];
  const float* WkT = ws + WS_WKT;
  const float* WdT = ws + WS_WDT;
  const float* a0T = ws + WS_A0T;
  const float* a1T = ws + WS_A1T;

  // ---- prologue: build B1f[8][4] = bf16(WkT + q_d*WdT) in registers ----
  short8 B1f[8][4];
  #pragma unroll
  for (int ks = 0; ks < 4; ++ks) {
    int d0 = ks * 32 + kgrp * 8;
    float4 q0 = *(const float4*)(query + (size_t)b * DD + d0);
    float4 q1 = *(const float4*)(query + (size_t)b * DD + d0 + 4);
    #pragma unroll
    for (int nt = 0; nt < 8; ++nt) {
      int h = nt * 16 + lr;
      float4 wk0 = *(const float4*)(WkT + h * 128 + d0);
      float4 wk1 = *(const float4*)(WkT + h * 128 + d0 + 4);
      float4 wd0 = *(const float4*)(WdT + h * 128 + d0);
      float4 wd1 = *(const float4*)(WdT + h * 128 + d0 + 4);
      short8 f;
      f[0] = (short)f2bf(wk0.x + q0.x * wd0.x);
      f[1] = (short)f2bf(wk0.y + q0.y * wd0.y);
      f[2] = (short)f2bf(wk0.z + q0.z * wd0.z);
      f[3] = (short)f2bf(wk0.w + q0.w * wd0.w);
      f[4] = (short)f2bf(wk1.x + q1.x * wd1.x);
      f[5] = (short)f2bf(wk1.y + q1.y * wd1.y);
      f[6] = (short)f2bf(wk1.z + q1.z * wd1.z);
      f[7] = (short)f2bf(wk1.w + q1.w * wd1.w);
      B1f[nt][ks] = f;
    }
  }
  // per-lane constants
  float qv[8];
  #pragma unroll
  for (int nt = 0; nt < 8; ++nt) qv[nt] = qas_g[(size_t)b * H1 + nt * 16 + lr];
  float b1v[4], wov[4];
  #pragma unroll
  for (int nt = 0; nt < 4; ++nt) {
    int g = nt * 16 + lr;
    b1v[nt] = b1[g]; wov[nt] = Wout[g];
  }
  const float bout0 = bout[0];

  // =============== barrier-free per-wave tile loop (13 tiles) ===============
  #pragma unroll 1
  for (int mt = 0; mt < 13; ++mt) {
    int tin = mt * 16 + lr; if (tin > 199) tin = 199;
    const float* kr = key + ((size_t)b * TT + tin) * DD;
    int tb = mt * 16 + kgrp * 4; if (tb > 196) tb = 196;

    // A-frags: load + cvt per ks
    short8 af[4];
    #pragma unroll
    for (int ks = 0; ks < 4; ++ks) {
      int d0 = ks * 32 + kgrp * 8;
      float4 k0 = *(const float4*)(kr + d0);
      float4 k1 = *(const float4*)(kr + d0 + 4);
      short8 f;
      f[0] = (short)f2bf(k0.x); f[1] = (short)f2bf(k0.y);
      f[2] = (short)f2bf(k0.z); f[3] = (short)f2bf(k0.w);
      f[4] = (short)f2bf(k1.x); f[5] = (short)f2bf(k1.y);
      f[6] = (short)f2bf(k1.z); f[7] = (short)f2bf(k1.w);
      af[ks] = f;
    }

    // ---- GEMM1 pass A (nt 0..3) ----
    {
      floatx4 acc[4];
      #pragma unroll
      for (int nt = 0; nt < 4; ++nt) {
        acc[nt][0] = qv[nt]; acc[nt][1] = qv[nt];
        acc[nt][2] = qv[nt]; acc[nt][3] = qv[nt];
      }
      #pragma unroll
      for (int ks = 0; ks < 4; ++ks)
        #pragma unroll
        for (int nt = 0; nt < 4; ++nt)
          acc[nt] = __builtin_amdgcn_mfma_f32_16x16x32_bf16(af[ks], B1f[nt][ks], acc[nt], 0, 0, 0);
      #pragma unroll
      for (int nt = 0; nt < 4; ++nt) {
        int h = nt * 16 + lr;
        float4 aq = *(const float4*)(a0T + h * 200 + tb);
        #pragma unroll
        for (int r = 0; r < 4; ++r) {
          int t_loc = kgrp * 4 + r;
          float v = acc[nt][r];
          float a = ((const float*)&aq)[r];
          v = v > 0.0f ? v : a * v;
          *(unsigned short*)(a2b + t_loc * 256 + ((h * 2) ^ ((t_loc & 7) << 4))) = f2bf(v);
        }
      }
    }
    // ---- GEMM1 pass B (nt 4..7) ----
    {
      floatx4 acc[4];
      #pragma unroll
      for (int nt = 0; nt < 4; ++nt) {
        acc[nt][0] = qv[nt + 4]; acc[nt][1] = qv[nt + 4];
        acc[nt][2] = qv[nt + 4]; acc[nt][3] = qv[nt + 4];
      }
      #pragma unroll
      for (int ks = 0; ks < 4; ++ks)
        #pragma unroll
        for (int nt = 0; nt < 4; ++nt)
          acc[nt] = __builtin_amdgcn_mfma_f32_16x16x32_bf16(af[ks], B1f[nt + 4][ks], acc[nt], 0, 0, 0);
      #pragma unroll
      for (int nt = 0; nt < 4; ++nt) {
        int h = (nt + 4) * 16 + lr;
        float4 aq = *(const float4*)(a0T + h * 200 + tb);
        #pragma unroll
        for (int r = 0; r < 4; ++r) {
          int t_loc = kgrp * 4 + r;
          float v = acc[nt][r];
          float a = ((const float*)&aq)[r];
          v = v > 0.0f ? v : a * v;
          *(unsigned short*)(a2b + t_loc * 256 + ((h * 2) ^ ((t_loc & 7) << 4))) = f2bf(v);
        }
      }
    }

    // ---- GEMM2 (wave-private A2; same-wave DS is in-order) ----
    short8 a2f[4];
    #pragma unroll
    for (int ks = 0; ks < 4; ++ks) {
      a2f[ks] = *(const short8*)(a2b + lr * 256 +
                                 ((ks * 64 + kgrp * 16) ^ ((lr & 7) << 4)));
    }
    floatx4 acc2[4];
    #pragma unroll
    for (int nt = 0; nt < 4; ++nt) acc2[nt] = (floatx4)(0.0f);
    #pragma unroll
    for (int ks = 0; ks < 4; ++ks) {
      #pragma unroll
      for (int nt = 0; nt < 4; ++nt) {
        int row = nt * 16 + lr;
        short8 bf = *(const short8*)((const char*)W1S + row * 256 +
                                     ((ks * 64 + kgrp * 16) ^ ((row & 7) << 4)));
        acc2[nt] = __builtin_amdgcn_mfma_f32_16x16x32_bf16(a2f[ks], bf, acc2[nt], 0, 0, 0);
      }
    }

    // ---- epilogue 2: +b1, PReLU(a1), *Wout, 16-lane reduce -> LG ----
    float p[4] = {0.f, 0.f, 0.f, 0.f};
    #pragma unroll
    for (int nt = 0; nt < 4; ++nt) {
      int g = nt * 16 + lr;
      float4 aq = *(const float4*)(a1T + g * 200 + tb);
      #pragma unroll
      for (int r = 0; r < 4; ++r) {
        float x = acc2[nt][r] + b1v[nt];
        float a = ((const float*)&aq)[r];
        x = x > 0.0f ? x : a * x;
        p[r] += x * wov[nt];
      }
    }
    #pragma unroll
    for (int m = 1; m < 16; m <<= 1) {
      #pragma unroll
      for (int r = 0; r < 4; ++r) p[r] += __shfl_xor(p[r], m);
    }
    if (lr == 0) {
      #pragma unroll
      for (int r = 0; r < 4; ++r) {
        int tg = mt * 16 + kgrp * 4 + r;
        if (tg < TT) LG[w][tg] = bout0 + p[r];
      }
    }
  }

  // =============== wave-local softmax (64-lane shfl) ===============
  asm volatile("s_waitcnt lgkmcnt(0)" ::: "memory");
  float lv[4];
  float mx = -INFINITY;
  #pragma unroll
  for (int j = 0; j < 4; ++j) {
    int t = l + 64 * j;
    if (t < TT) {
      float lg = LG[w][t];
      int mk = mask[(size_t)b * TT + t];
      lv[j] = (mk == 0) ? MASK_PAD : lg;
    } else lv[j] = -INFINITY;
    mx = fmaxf(mx, lv[j]);
  }
  #pragma unroll
  for (int off = 32; off >= 1; off >>= 1) mx = fmaxf(mx, __shfl_xor(mx, off));
  float e[4];
  float s = 0.0f;
  #pragma unroll
  for (int j = 0; j < 4; ++j) {
    int t = l + 64 * j;
    e[j] = (t < TT) ? __expf(lv[j] - mx) : 0.0f;
    s += e[j];
  }
  #pragma unroll
  for (int off = 32; off >= 1; off >>= 1) s += __shfl_xor(s, off);
  float inv = 1.0f / s;
  #pragma unroll
  for (int j = 0; j < 4; ++j) {
    int t = l + 64 * j;
    if (t < TT) attn_out[(size_t)b * TT + t] = e[j] * inv;
  }
}

// ---------------------------------------------------------------------------
// PV: out[b][d] = sum_t attn[b][t] * val[b][t][d].
// ---------------------------------------------------------------------------
__global__ __launch_bounds__(256) void din_pv(
    const float* __restrict__ val, const float* __restrict__ attn,
    float* __restrict__ out) {
  const int b = blockIdx.x;
  const int tid = threadIdx.x;
  __shared__ float eL[TT];
  __shared__ float red[8 * DD];

  if (tid < TT) eL[tid] = attn[(size_t)b * TT + tid];
  __syncthreads();

  const int group = tid >> 5;
  const int d4 = (tid & 31) * 4;
  const float* vb = val + (size_t)b * TT * DD;
  float4 acc4 = make_float4(0.f, 0.f, 0.f, 0.f);
  #pragma unroll 5
  for (int t = group * 25; t < group * 25 + 25; ++t) {
    float4 v = *(const float4*)(vb + (size_t)t * DD + d4);
    float wt = eL[t];
    acc4.x += wt * v.x; acc4.y += wt * v.y;
    acc4.z += wt * v.z; acc4.w += wt * v.w;
  }
  *(float4*)&red[group * DD + d4] = acc4;
  __syncthreads();
  if (tid < DD) {
    float s = 0.0f;
    #pragma unroll
    for (int g = 0; g < 8; ++g) s += red[g * DD + tid];
    out[(size_t)b * DD + tid] = s;
  }
}

extern "C" void kernel_launch(void* const* d_in, const int* in_sizes, int n_in,
                              void* d_out, int out_size, void* d_ws, size_t ws_size,
                              hipStream_t stream) {
  const float* query = (const float*)d_in[0];
  const float* key   = (const float*)d_in[1];
  const float* val   = (const float*)d_in[2];
  const int*   mask  = (const int*)d_in[3];
  const float* W0    = (const float*)d_in[4];
  const float* b0    = (const float*)d_in[5];
  const float* a0    = (const float*)d_in[6];
  const float* W1    = (const float*)d_in[7];
  const float* b1    = (const float*)d_in[8];
  const float* a1    = (const float*)d_in[9];
  const float* Wout  = (const float*)d_in[10];
  const float* bout  = (const float*)d_in[11];
  float* out = (float*)d_out;
  float* ws  = (float*)d_ws;
  float* qas_g = ws + WS_QAS;
  float* attn  = ws + WS_ATTN;

  hipLaunchKernelGGL(din_fold, dim3(246), dim3(256), 0, stream, W0, W1, a0, a1, ws);
  hipLaunchKernelGGL(din_qa, dim3(BB), dim3(128), 0, stream, query, b0, ws, qas_g);
  hipLaunchKernelGGL(din_logits, dim3(512), dim3(256), 0, stream,
                     key, query, mask, ws, qas_g, b1, Wout, bout, attn);
  hipLaunchKernelGGL(din_pv, dim3(BB), dim3(256), 0, stream, val, attn, out);
}